// Round 1
// baseline (870.731 us; speedup 1.0000x reference)
//
#include <hip/hip_runtime.h>
#include <math.h>

typedef unsigned short u16;
typedef unsigned int u32;
typedef __bf16 bf16x8 __attribute__((ext_vector_type(8)));
typedef float f32x4 __attribute__((ext_vector_type(4)));

#define NB 1024   // batch
#define HID 1024

__device__ __forceinline__ float bfu(u16 u) { return __uint_as_float(((u32)u) << 16); }
__device__ __forceinline__ u16 f2bf(float f) {
    u32 u = __float_as_uint(f);
    return (u16)((u + 0x7fffu + ((u >> 16) & 1u)) >> 16);
}
__device__ __forceinline__ void unpack8(uint4 v, float* f) {
    f[0] = bfu((u16)(v.x & 0xffffu)); f[1] = bfu((u16)(v.x >> 16));
    f[2] = bfu((u16)(v.y & 0xffffu)); f[3] = bfu((u16)(v.y >> 16));
    f[4] = bfu((u16)(v.z & 0xffffu)); f[5] = bfu((u16)(v.z >> 16));
    f[6] = bfu((u16)(v.w & 0xffffu)); f[7] = bfu((u16)(v.w >> 16));
}

#if __has_builtin(__builtin_amdgcn_global_load_lds)
#define HAVE_GLL 1
#else
#define HAVE_GLL 0
#endif

// Stage 16B per lane: global -> LDS. ldsbase must be wave-uniform; HW (or
// fallback) writes to ldsbase + lane*16.
__device__ __forceinline__ void stage16(const void* g, void* ldsbase, int lane) {
#if HAVE_GLL
    typedef const __attribute__((address_space(1))) unsigned char ga_t;
    typedef __attribute__((address_space(3))) unsigned char la_t;
    __builtin_amdgcn_global_load_lds((ga_t*)(unsigned long long)g,
                                     (la_t*)(u32)(unsigned long long)ldsbase,
                                     16, 0, 0);
#else
    *reinterpret_cast<uint4*>((char*)ldsbase + lane * 16) =
        *reinterpret_cast<const uint4*>(g);
#endif
}

// Stage a 128 x 64 bf16 tile (rows from a row-major source with leading dim
// ld, 64 contiguous elements each) into dst[128*64] (row stride 64).
__device__ __forceinline__ void stage_tile(const u16* src, int ld, u16* dst, int tid) {
    int w = tid >> 6, lane = tid & 63;
#pragma unroll
    for (int q = 0; q < 4; ++q) {
        int rbase = q * 32 + w * 8;
        int row = rbase + (lane >> 3);
        stage16(src + (size_t)row * ld + (lane & 7) * 8, dst + rbase * 64, lane);
    }
}

// 4 waves (2x2), each wave computes a 64x64 sub-tile as 4x4 fragments of
// 16x16x32 bf16 MFMA. As/Bs are [128][64] bf16 (A rows = M, B rows = N).
__device__ __forceinline__ void mfma_block(const u16* As, const u16* Bs,
                                           f32x4 acc[4][4], int wr, int wc, int lane) {
    int lr = lane >> 4, lc = lane & 15;
#pragma unroll
    for (int kc = 0; kc < 64; kc += 32) {
        bf16x8 av[4], bv[4];
#pragma unroll
        for (int it = 0; it < 4; ++it)
            av[it] = *(const bf16x8*)&As[(wr * 64 + it * 16 + lc) * 64 + kc + lr * 8];
#pragma unroll
        for (int nt = 0; nt < 4; ++nt)
            bv[nt] = *(const bf16x8*)&Bs[(wc * 64 + nt * 16 + lc) * 64 + kc + lr * 8];
#pragma unroll
        for (int it = 0; it < 4; ++it)
#pragma unroll
            for (int nt = 0; nt < 4; ++nt)
                acc[it][nt] = __builtin_amdgcn_mfma_f32_16x16x32_bf16(
                    av[it], bv[nt], acc[it][nt], 0, 0, 0);
    }
}

__global__ __launch_bounds__(256) void k_cast(const float* in, u16* out, int n) {
    int i = blockIdx.x * 256 + threadIdx.x;
    if (i < n) out[i] = f2bf(in[i]);
}

// out[c*R + r] = bf16(in[r*C + c]); R,C multiples of 32.
__global__ __launch_bounds__(256) void k_transpose(const float* in, u16* out, int R, int C) {
    __shared__ u16 tile[32][33];
    int c0 = blockIdx.x * 32, r0 = blockIdx.y * 32;
    int tx = threadIdx.x, ty = threadIdx.y;  // (32, 8)
#pragma unroll
    for (int dy = 0; dy < 32; dy += 8)
        tile[ty + dy][tx] = f2bf(in[(size_t)(r0 + ty + dy) * C + c0 + tx]);
    __syncthreads();
#pragma unroll
    for (int dy = 0; dy < 32; dy += 8)
        out[(size_t)(c0 + ty + dy) * R + r0 + tx] = tile[tx][ty + dy];
}

// Layer 1, fp32: h1 = tanh([mu,t] @ W1 + b1) for drift and noise nets.
// 8 samples per block, 256 threads.
__global__ __launch_bounds__(256) void k_layer1(const float* states, const float* tptr,
                                                const float* dW1, const float* db1,
                                                const float* nW1, const float* nb1,
                                                u16* h1d, u16* h1n) {
    __shared__ float xt[129][8];
    int blk = blockIdx.x, tid = threadIdx.x;
    float t = *tptr;
    for (int idx = tid; idx < 8 * 128; idx += 256) {
        int d = idx >> 3, s = idx & 7;
        xt[d][s] = states[(size_t)(blk * 8 + s) * 256 + d];
    }
    if (tid < 8) xt[128][tid] = t;
    __syncthreads();
#pragma unroll
    for (int net = 0; net < 2; ++net) {
        const float* W = net ? nW1 : dW1;
        const float* bi = net ? nb1 : db1;
        u16* H = net ? h1n : h1d;
        for (int c0 = 0; c0 < 1024; c0 += 256) {
            int o = c0 + tid;
            float acc[8] = {0.f, 0.f, 0.f, 0.f, 0.f, 0.f, 0.f, 0.f};
            for (int d = 0; d < 129; ++d) {
                float w = W[(size_t)d * 1024 + o];
                float4 xa = *(const float4*)&xt[d][0];
                float4 xb = *(const float4*)&xt[d][4];
                acc[0] += xa.x * w; acc[1] += xa.y * w; acc[2] += xa.z * w; acc[3] += xa.w * w;
                acc[4] += xb.x * w; acc[5] += xb.y * w; acc[6] += xb.z * w; acc[7] += xb.w * w;
            }
            float b = bi[o];
#pragma unroll
            for (int s = 0; s < 8; ++s)
                H[(size_t)(blk * 8 + s) * 1024 + o] = f2bf(tanhf(acc[s] + b));
        }
    }
}

// Layer 2: h2 = tanh(h1 @ W2 + b2), bf16 MFMA. WT is W2 transposed (N x K).
__global__ __launch_bounds__(256) void k_gemm_tanh(const u16* Ad, const u16* An,
                                                   const u16* Wd, const u16* Wn,
                                                   const float* bd, const float* bn,
                                                   u16* Od, u16* On) {
    int z = blockIdx.z;
    const u16* A = z ? An : Ad;
    const u16* W = z ? Wn : Wd;
    const float* bias = z ? bn : bd;
    u16* O = z ? On : Od;
    int n0 = blockIdx.x * 128, row0 = blockIdx.y * 128;
    __shared__ u16 As[128 * 64], Bs[128 * 64];
    int tid = threadIdx.x, w = tid >> 6, lane = tid & 63;
    int wr = w >> 1, wc = w & 1, lr = lane >> 4, lc = lane & 15;
    f32x4 acc[4][4];
#pragma unroll
    for (int a = 0; a < 4; ++a)
#pragma unroll
        for (int b2 = 0; b2 < 4; ++b2) { f32x4 zz = {0.f, 0.f, 0.f, 0.f}; acc[a][b2] = zz; }
    for (int k0 = 0; k0 < 1024; k0 += 64) {
        stage_tile(A + (size_t)row0 * 1024 + k0, 1024, As, tid);
        stage_tile(W + (size_t)n0 * 1024 + k0, 1024, Bs, tid);
        __syncthreads();
        mfma_block(As, Bs, acc, wr, wc, lane);
        __syncthreads();
    }
#pragma unroll
    for (int it = 0; it < 4; ++it)
#pragma unroll
        for (int nt = 0; nt < 4; ++nt) {
            int col = n0 + wc * 64 + nt * 16 + lc;
            float b = bias[col];
#pragma unroll
            for (int r = 0; r < 4; ++r) {
                int row = row0 + wr * 64 + it * 16 + lr * 4 + r;
                O[(size_t)row * 1024 + col] = f2bf(tanhf(acc[it][nt][r] + b));
            }
        }
}

// Layer 3: z=0 -> mu_drift into out[:,0:128] (f32); z=1 -> Q = softplus into Qws.
__global__ __launch_bounds__(256) void k_gemm_l3(const u16* Ad, const u16* An,
                                                 const u16* Wd, const u16* Wn,
                                                 const float* bd, const float* bn,
                                                 float* out0, float* Qws) {
    int z = blockIdx.z;
    const u16* A = z ? An : Ad;
    const u16* W = z ? Wn : Wd;
    const float* bias = z ? bn : bd;
    int row0 = blockIdx.y * 128;
    __shared__ u16 As[128 * 64], Bs[128 * 64];
    int tid = threadIdx.x, w = tid >> 6, lane = tid & 63;
    int wr = w >> 1, wc = w & 1, lr = lane >> 4, lc = lane & 15;
    f32x4 acc[4][4];
#pragma unroll
    for (int a = 0; a < 4; ++a)
#pragma unroll
        for (int b2 = 0; b2 < 4; ++b2) { f32x4 zz = {0.f, 0.f, 0.f, 0.f}; acc[a][b2] = zz; }
    for (int k0 = 0; k0 < 1024; k0 += 64) {
        stage_tile(A + (size_t)row0 * 1024 + k0, 1024, As, tid);
        stage_tile(W + (size_t)k0, 1024, Bs, tid);  // n0 = 0, N = 128
        __syncthreads();
        mfma_block(As, Bs, acc, wr, wc, lane);
        __syncthreads();
    }
#pragma unroll
    for (int it = 0; it < 4; ++it)
#pragma unroll
        for (int nt = 0; nt < 4; ++nt) {
            int col = wc * 64 + nt * 16 + lc;
            float b = bias[col];
#pragma unroll
            for (int r = 0; r < 4; ++r) {
                int row = row0 + wr * 64 + it * 16 + lr * 4 + r;
                float v = acc[it][nt][r] + b;
                if (z == 0) {
                    out0[(size_t)row * 256 + col] = v;
                } else {
                    float sp = (v > 20.f) ? v : log1pf(expf(v));
                    Qws[(size_t)row * 128 + col] = sp;
                }
            }
        }
}

// Jacobian diagonal: per (sample b, k2-block kb) compute
// U2[i,k2] = sum_j (dW1[i,j]*g1[j]) * dW2[j,k2], then
// Jpart[b,kb,i] = sum_{k2 in block} U2[i,k2] * g2[k2] * dW3[k2,i].
__global__ __launch_bounds__(256) void k_jac(const u16* dW1bf, const u16* W2T,
                                             const u16* W3T, const u16* h1d,
                                             const u16* h2d, float* Jpart) {
    int kb = blockIdx.x;   // 0..7
    int b = blockIdx.y;    // 0..1023
    int n0 = kb * 128;
    __shared__ u16 As[128 * 64], Bs[128 * 64];
    __shared__ float g2s[128];
    __shared__ float jtmp[2][128];
    int tid = threadIdx.x, w = tid >> 6, lane = tid & 63;
    int wr = w >> 1, wc = w & 1, lr = lane >> 4, lc = lane & 15;

    if (tid < 128) {
        float h = bfu(h2d[(size_t)b * 1024 + n0 + tid]);
        g2s[tid] = 1.f - h * h;
    }
    f32x4 acc[4][4];
#pragma unroll
    for (int a = 0; a < 4; ++a)
#pragma unroll
        for (int b2 = 0; b2 < 4; ++b2) { f32x4 zz = {0.f, 0.f, 0.f, 0.f}; acc[a][b2] = zz; }

    for (int k0 = 0; k0 < 1024; k0 += 64) {
        // B tile: dW2T rows n0..n0+127, cols k0..k0+63 (async direct-to-LDS)
        stage_tile(W2T + (size_t)n0 * 1024 + k0, 1024, Bs, tid);
        // A tile: dW1bf row i scaled by g1[j] = 1 - h1^2 (reg-staged)
        {
            int seg = tid & 7;
            int j8 = k0 + seg * 8;
            uint4 hv = *(const uint4*)&h1d[(size_t)b * 1024 + j8];
            float hf[8], g[8];
            unpack8(hv, hf);
#pragma unroll
            for (int e = 0; e < 8; ++e) g[e] = 1.f - hf[e] * hf[e];
#pragma unroll
            for (int q = 0; q < 4; ++q) {
                int row = q * 32 + (tid >> 3);
                uint4 wv = *(const uint4*)&dW1bf[(size_t)row * 1024 + j8];
                float wf[8];
                unpack8(wv, wf);
                uint4 o;
                o.x = (u32)f2bf(wf[0] * g[0]) | ((u32)f2bf(wf[1] * g[1]) << 16);
                o.y = (u32)f2bf(wf[2] * g[2]) | ((u32)f2bf(wf[3] * g[3]) << 16);
                o.z = (u32)f2bf(wf[4] * g[4]) | ((u32)f2bf(wf[5] * g[5]) << 16);
                o.w = (u32)f2bf(wf[6] * g[6]) | ((u32)f2bf(wf[7] * g[7]) << 16);
                *(uint4*)&As[row * 64 + seg * 8] = o;
            }
        }
        __syncthreads();
        mfma_block(As, Bs, acc, wr, wc, lane);
        __syncthreads();
    }

    // Fused diag contraction: C layout col = lane&15, row = (lane>>4)*4 + r
#pragma unroll
    for (int it = 0; it < 4; ++it) {
#pragma unroll
        for (int r = 0; r < 4; ++r) {
            int i = wr * 64 + it * 16 + lr * 4 + r;
            float p = 0.f;
#pragma unroll
            for (int kt = 0; kt < 4; ++kt) {
                int k2l = wc * 64 + kt * 16 + lc;
                float w3 = bfu(W3T[(size_t)i * 1024 + n0 + k2l]);
                p += acc[it][kt][r] * g2s[k2l] * w3;
            }
#pragma unroll
            for (int m = 1; m < 16; m <<= 1) p += __shfl_xor(p, m, 64);
            if (lc == 0) jtmp[wc][i] = p;
        }
    }
    __syncthreads();
    if (tid < 128)
        Jpart[((size_t)b * 8 + kb) * 128 + tid] = jtmp[0][tid] + jtmp[1][tid];
}

// sigma_drift and log-density drift.
__global__ __launch_bounds__(128) void k_final(const float* states, const float* Jpart,
                                               const float* Qws, float* out) {
    int b = blockIdx.x, i = threadIdx.x;
    float jd = 0.f;
#pragma unroll
    for (int kb = 0; kb < 8; ++kb) jd += Jpart[((size_t)b * 8 + kb) * 128 + i];
    float sig = states[(size_t)b * 256 + 128 + i];
    float q = Qws[(size_t)b * 128 + i];
    out[(size_t)b * 256 + 128 + i] = 2.f * jd * sig + q;
    float s1 = jd;
    float s2 = q / (sig + 1e-6f);
#pragma unroll
    for (int m = 32; m >= 1; m >>= 1) {
        s1 += __shfl_down(s1, m, 64);
        s2 += __shfl_down(s2, m, 64);
    }
    __shared__ float red[4];
    int wv = i >> 6, ln = i & 63;
    if (ln == 0) { red[wv * 2] = s1; red[wv * 2 + 1] = s2; }
    __syncthreads();
    if (i == 0) out[(size_t)NB * 256 + b] = -(red[0] + red[2]) + 0.5f * (red[1] + red[3]);
}

extern "C" void kernel_launch(void* const* d_in, const int* in_sizes, int n_in,
                              void* d_out, int out_size, void* d_ws, size_t ws_size,
                              hipStream_t stream) {
    (void)in_sizes; (void)n_in; (void)out_size; (void)ws_size;
    const float* states = (const float*)d_in[0];
    const float* tptr   = (const float*)d_in[1];
    const float* dW1 = (const float*)d_in[2];  const float* db1 = (const float*)d_in[3];
    const float* dW2 = (const float*)d_in[4];  const float* db2 = (const float*)d_in[5];
    const float* dW3 = (const float*)d_in[6];  const float* db3 = (const float*)d_in[7];
    const float* nW1 = (const float*)d_in[8];  const float* nb1 = (const float*)d_in[9];
    const float* nW2 = (const float*)d_in[10]; const float* nb2 = (const float*)d_in[11];
    const float* nW3 = (const float*)d_in[12]; const float* nb3 = (const float*)d_in[13];
    float* out = (float*)d_out;
    char* ws = (char*)d_ws;

    // workspace layout (bytes)
    u16* dW1bf = (u16*)(ws + 0);          //  128x1024 bf16      256 KiB
    u16* dW2T  = (u16*)(ws + 262144);     // 1024x1024 bf16 (T)    2 MiB
    u16* nW2T  = (u16*)(ws + 2359296);    //                       2 MiB
    u16* dW3T  = (u16*)(ws + 4456448);    //  128x1024 bf16 (T)  256 KiB
    u16* nW3T  = (u16*)(ws + 4718592);    //                     256 KiB
    u16* h1d   = (u16*)(ws + 4980736);    // 1024x1024 bf16        2 MiB
    u16* h1n   = (u16*)(ws + 7077888);
    u16* h2d   = (u16*)(ws + 9175040);
    u16* h2n   = (u16*)(ws + 11272192);
    float* Qws   = (float*)(ws + 13369344);  // 1024x128 f32      512 KiB
    float* Jpart = (float*)(ws + 13893632);  // 1024x8x128 f32      4 MiB
    // total ~17.3 MiB

    k_cast<<<512, 256, 0, stream>>>(dW1, dW1bf, 128 * 1024);
    dim3 tb(32, 8);
    k_transpose<<<dim3(32, 32), tb, 0, stream>>>(dW2, dW2T, 1024, 1024);
    k_transpose<<<dim3(32, 32), tb, 0, stream>>>(nW2, nW2T, 1024, 1024);
    k_transpose<<<dim3(4, 32), tb, 0, stream>>>(dW3, dW3T, 1024, 128);
    k_transpose<<<dim3(4, 32), tb, 0, stream>>>(nW3, nW3T, 1024, 128);
    k_layer1<<<128, 256, 0, stream>>>(states, tptr, dW1, db1, nW1, nb1, h1d, h1n);
    k_gemm_tanh<<<dim3(8, 8, 2), 256, 0, stream>>>(h1d, h1n, dW2T, nW2T, db2, nb2, h2d, h2n);
    k_gemm_l3<<<dim3(1, 8, 2), 256, 0, stream>>>(h2d, h2n, dW3T, nW3T, db3, nb3, out, Qws);
    k_jac<<<dim3(8, 1024), 256, 0, stream>>>(dW1bf, dW2T, dW3T, h1d, h2d, Jpart);
    k_final<<<1024, 128, 0, stream>>>(states, Jpart, Qws, out);
}

// Round 2
// 752.427 us; speedup vs baseline: 1.1572x; 1.1572x over previous
//
#include <hip/hip_runtime.h>
#include <math.h>

typedef unsigned short u16;
typedef unsigned int u32;
typedef __bf16 bf16x8 __attribute__((ext_vector_type(8)));
typedef float f32x4 __attribute__((ext_vector_type(4)));

#define NB 1024   // batch
#define HID 1024

__device__ __forceinline__ float bfu(u16 u) { return __uint_as_float(((u32)u) << 16); }
__device__ __forceinline__ u16 f2bf(float f) {
    u32 u = __float_as_uint(f);
    return (u16)((u + 0x7fffu + ((u >> 16) & 1u)) >> 16);
}
__device__ __forceinline__ u32 pack2(float a, float b) {
    return (u32)f2bf(a) | ((u32)f2bf(b) << 16);
}
__device__ __forceinline__ void unpack8(uint4 v, float* f) {
    f[0] = bfu((u16)(v.x & 0xffffu)); f[1] = bfu((u16)(v.x >> 16));
    f[2] = bfu((u16)(v.y & 0xffffu)); f[3] = bfu((u16)(v.y >> 16));
    f[4] = bfu((u16)(v.z & 0xffffu)); f[5] = bfu((u16)(v.z >> 16));
    f[6] = bfu((u16)(v.w & 0xffffu)); f[7] = bfu((u16)(v.w >> 16));
}

#if __has_builtin(__builtin_amdgcn_global_load_lds)
#define HAVE_GLL 1
#else
#define HAVE_GLL 0
#endif

// Stage 16B per lane: global -> LDS. ldsbase must be wave-uniform; HW (or
// fallback) writes to ldsbase + lane*16.
__device__ __forceinline__ void stage16(const void* g, void* ldsbase, int lane) {
#if HAVE_GLL
    typedef const __attribute__((address_space(1))) unsigned char ga_t;
    typedef __attribute__((address_space(3))) unsigned char la_t;
    __builtin_amdgcn_global_load_lds((ga_t*)(unsigned long long)g,
                                     (la_t*)(u32)(unsigned long long)ldsbase,
                                     16, 0, 0);
#else
    *reinterpret_cast<uint4*>((char*)ldsbase + lane * 16) =
        *reinterpret_cast<const uint4*>(g);
#endif
}

// Stage a 128 x 64 bf16 tile (rows from a row-major source with leading dim
// ld, 64 contiguous elements each) into dst[128*64] (row stride 64).
__device__ __forceinline__ void stage_tile(const u16* src, int ld, u16* dst, int tid) {
    int w = tid >> 6, lane = tid & 63;
#pragma unroll
    for (int q = 0; q < 4; ++q) {
        int rbase = q * 32 + w * 8;
        int row = rbase + (lane >> 3);
        stage16(src + (size_t)row * ld + (lane & 7) * 8, dst + rbase * 64, lane);
    }
}

// 4 waves (2x2), each wave computes a 64x64 sub-tile as 4x4 fragments of
// 16x16x32 bf16 MFMA. As/Bs are [128][64] bf16 (A rows = M, B rows = N).
__device__ __forceinline__ void mfma_block(const u16* As, const u16* Bs,
                                           f32x4 acc[4][4], int wr, int wc, int lane) {
    int lr = lane >> 4, lc = lane & 15;
#pragma unroll
    for (int kc = 0; kc < 64; kc += 32) {
        bf16x8 av[4], bv[4];
#pragma unroll
        for (int it = 0; it < 4; ++it)
            av[it] = *(const bf16x8*)&As[(wr * 64 + it * 16 + lc) * 64 + kc + lr * 8];
#pragma unroll
        for (int nt = 0; nt < 4; ++nt)
            bv[nt] = *(const bf16x8*)&Bs[(wc * 64 + nt * 16 + lc) * 64 + kc + lr * 8];
#pragma unroll
        for (int it = 0; it < 4; ++it)
#pragma unroll
            for (int nt = 0; nt < 4; ++nt)
                acc[it][nt] = __builtin_amdgcn_mfma_f32_16x16x32_bf16(
                    av[it], bv[nt], acc[it][nt], 0, 0, 0);
    }
}

__global__ __launch_bounds__(256) void k_cast(const float* in, u16* out, int n) {
    int i = blockIdx.x * 256 + threadIdx.x;
    if (i < n) out[i] = f2bf(in[i]);
}

// out[c*R + r] = bf16(in[r*C + c]); R,C multiples of 32.
__global__ __launch_bounds__(256) void k_transpose(const float* in, u16* out, int R, int C) {
    __shared__ u16 tile[32][33];
    int c0 = blockIdx.x * 32, r0 = blockIdx.y * 32;
    int tx = threadIdx.x, ty = threadIdx.y;  // (32, 8)
#pragma unroll
    for (int dy = 0; dy < 32; dy += 8)
        tile[ty + dy][tx] = f2bf(in[(size_t)(r0 + ty + dy) * C + c0 + tx]);
    __syncthreads();
#pragma unroll
    for (int dy = 0; dy < 32; dy += 8)
        out[(size_t)(c0 + ty + dy) * R + r0 + tx] = tile[tx][ty + dy];
}

// Layer 1, fp32: h1 = tanh([mu,t] @ W1 + b1) for drift and noise nets.
// grid (128 sample-groups, 4 col-quarters, 2 nets); 8 samples per block.
// Also emits g1 = 1 - h1^2 (bf16) for the drift net (needed by k_scaleA).
__global__ __launch_bounds__(256) void k_layer1(const float* states, const float* tptr,
                                                const float* dW1, const float* db1,
                                                const float* nW1, const float* nb1,
                                                u16* h1d, u16* h1n, u16* g1d) {
    __shared__ float xt[129][8];
    int blk = blockIdx.x, q = blockIdx.y, net = blockIdx.z, tid = threadIdx.x;
    float t = *tptr;
    for (int idx = tid; idx < 8 * 128; idx += 256) {
        int d = idx >> 3, s = idx & 7;
        xt[d][s] = states[(size_t)(blk * 8 + s) * 256 + d];
    }
    if (tid < 8) xt[128][tid] = t;
    __syncthreads();
    const float* W = net ? nW1 : dW1;
    const float* bi = net ? nb1 : db1;
    u16* H = net ? h1n : h1d;
    int o = q * 256 + tid;
    float acc[8] = {0.f, 0.f, 0.f, 0.f, 0.f, 0.f, 0.f, 0.f};
    for (int d = 0; d < 129; ++d) {
        float w = W[(size_t)d * 1024 + o];
        float4 xa = *(const float4*)&xt[d][0];
        float4 xb = *(const float4*)&xt[d][4];
        acc[0] += xa.x * w; acc[1] += xa.y * w; acc[2] += xa.z * w; acc[3] += xa.w * w;
        acc[4] += xb.x * w; acc[5] += xb.y * w; acc[6] += xb.z * w; acc[7] += xb.w * w;
    }
    float b = bi[o];
#pragma unroll
    for (int s = 0; s < 8; ++s) {
        float h = tanhf(acc[s] + b);
        H[(size_t)(blk * 8 + s) * 1024 + o] = f2bf(h);
        if (!net) g1d[(size_t)(blk * 8 + s) * 1024 + o] = f2bf(1.f - h * h);
    }
}

// Layer 2: h2 = tanh(h1 @ W2 + b2), bf16 MFMA. WT is W2 transposed (N x K).
__global__ __launch_bounds__(256) void k_gemm_tanh(const u16* Ad, const u16* An,
                                                   const u16* Wd, const u16* Wn,
                                                   const float* bd, const float* bn,
                                                   u16* Od, u16* On) {
    int z = blockIdx.z;
    const u16* A = z ? An : Ad;
    const u16* W = z ? Wn : Wd;
    const float* bias = z ? bn : bd;
    u16* O = z ? On : Od;
    int n0 = blockIdx.x * 128, row0 = blockIdx.y * 128;
    __shared__ __align__(16) u16 As[128 * 64], Bs[128 * 64];
    int tid = threadIdx.x, w = tid >> 6, lane = tid & 63;
    int wr = w >> 1, wc = w & 1, lr = lane >> 4, lc = lane & 15;
    f32x4 acc[4][4];
#pragma unroll
    for (int a = 0; a < 4; ++a)
#pragma unroll
        for (int b2 = 0; b2 < 4; ++b2) { f32x4 zz = {0.f, 0.f, 0.f, 0.f}; acc[a][b2] = zz; }
    for (int k0 = 0; k0 < 1024; k0 += 64) {
        stage_tile(A + (size_t)row0 * 1024 + k0, 1024, As, tid);
        stage_tile(W + (size_t)n0 * 1024 + k0, 1024, Bs, tid);
        __syncthreads();
        mfma_block(As, Bs, acc, wr, wc, lane);
        __syncthreads();
    }
#pragma unroll
    for (int it = 0; it < 4; ++it)
#pragma unroll
        for (int nt = 0; nt < 4; ++nt) {
            int col = n0 + wc * 64 + nt * 16 + lc;
            float b = bias[col];
#pragma unroll
            for (int r = 0; r < 4; ++r) {
                int row = row0 + wr * 64 + it * 16 + lr * 4 + r;
                O[(size_t)row * 1024 + col] = f2bf(tanhf(acc[it][nt][r] + b));
            }
        }
}

// Layer 3: z=0 -> mu_drift into out[:,0:128] (f32); z=1 -> Q = softplus into Qws.
__global__ __launch_bounds__(256) void k_gemm_l3(const u16* Ad, const u16* An,
                                                 const u16* Wd, const u16* Wn,
                                                 const float* bd, const float* bn,
                                                 float* out0, float* Qws) {
    int z = blockIdx.z;
    const u16* A = z ? An : Ad;
    const u16* W = z ? Wn : Wd;
    const float* bias = z ? bn : bd;
    int row0 = blockIdx.y * 128;
    __shared__ __align__(16) u16 As[128 * 64], Bs[128 * 64];
    int tid = threadIdx.x, w = tid >> 6, lane = tid & 63;
    int wr = w >> 1, wc = w & 1, lr = lane >> 4, lc = lane & 15;
    f32x4 acc[4][4];
#pragma unroll
    for (int a = 0; a < 4; ++a)
#pragma unroll
        for (int b2 = 0; b2 < 4; ++b2) { f32x4 zz = {0.f, 0.f, 0.f, 0.f}; acc[a][b2] = zz; }
    for (int k0 = 0; k0 < 1024; k0 += 64) {
        stage_tile(A + (size_t)row0 * 1024 + k0, 1024, As, tid);
        stage_tile(W + (size_t)k0, 1024, Bs, tid);  // n0 = 0, N = 128
        __syncthreads();
        mfma_block(As, Bs, acc, wr, wc, lane);
        __syncthreads();
    }
#pragma unroll
    for (int it = 0; it < 4; ++it)
#pragma unroll
        for (int nt = 0; nt < 4; ++nt) {
            int col = wc * 64 + nt * 16 + lc;
            float b = bias[col];
#pragma unroll
            for (int r = 0; r < 4; ++r) {
                int row = row0 + wr * 64 + it * 16 + lr * 4 + r;
                float v = acc[it][nt][r] + b;
                if (z == 0) {
                    out0[(size_t)row * 256 + col] = v;
                } else {
                    float sp = (v > 20.f) ? v : log1pf(expf(v));
                    Qws[(size_t)row * 128 + col] = sp;
                }
            }
        }
}

// Materialize Asc[s_local][i][j] = dW1bf[i][j] * g1[b][j]  (bf16, once per sample).
// grid: CS blocks (one sample each), 256 threads; 16384 uint4 stores per block.
__global__ __launch_bounds__(256) void k_scaleA(const u16* dW1bf, const u16* g1d,
                                                u16* Asc, int c0) {
    int sl = blockIdx.x;
    size_t b = (size_t)(c0 + sl);
    const u16* g1 = g1d + b * 1024;
    u16* dst = Asc + (size_t)sl * (128 * 1024);
    int tid = threadIdx.x;
    for (int idx = tid; idx < 128 * 128; idx += 256) {
        int row = idx >> 7, jc = idx & 127;
        int j0 = jc * 8;
        uint4 wv = *(const uint4*)&dW1bf[(size_t)row * 1024 + j0];
        uint4 gv = *(const uint4*)&g1[j0];
        float wf[8], gf[8];
        unpack8(wv, wf);
        unpack8(gv, gf);
        uint4 o;
        o.x = pack2(wf[0] * gf[0], wf[1] * gf[1]);
        o.y = pack2(wf[2] * gf[2], wf[3] * gf[3]);
        o.z = pack2(wf[4] * gf[4], wf[5] * gf[5]);
        o.w = pack2(wf[6] * gf[6], wf[7] * gf[7]);
        *(uint4*)&dst[(size_t)row * 1024 + j0] = o;
    }
}

// Pure-load batched GEMM + fused diagonal contraction.
// U[i,k2] = sum_j Asc[s][i,j] * dW2T[k2,j];
// Jpart[b,kb,i] = sum_{k2 in kb-block} U[i,k2] * g2[k2] * dW3T[i,k2].
// blockIdx remapped so all 8 kb-blocks of one sample land on one XCD
// (ids congruent mod 8 share an XCD): A panel is read once into that L2.
__global__ __launch_bounds__(256) void k_jacgemm(const u16* Asc, const u16* W2T,
                                                 const u16* W3T, const u16* h2d,
                                                 float* Jpart, int c0, int CS) {
    int lin = blockIdx.x;
    int x = lin & 7, jj = lin >> 3;
    int sl = x * (CS >> 3) + ((jj >> 6) << 3) + ((jj >> 3) & 7);
    int kb = jj & 7;
    int b = c0 + sl;
    int n0 = kb * 128;
    __shared__ __align__(16) u16 As[128 * 64], Bs[128 * 64];
    __shared__ float g2s[128];
    __shared__ float jtmp[2][128];
    int tid = threadIdx.x, w = tid >> 6, lane = tid & 63;
    int wr = w >> 1, wc = w & 1, lr = lane >> 4, lc = lane & 15;

    if (tid < 128) {
        float h = bfu(h2d[(size_t)b * 1024 + n0 + tid]);
        g2s[tid] = 1.f - h * h;
    }
    f32x4 acc[4][4];
#pragma unroll
    for (int a = 0; a < 4; ++a)
#pragma unroll
        for (int b2 = 0; b2 < 4; ++b2) { f32x4 zz = {0.f, 0.f, 0.f, 0.f}; acc[a][b2] = zz; }

    const u16* Apanel = Asc + (size_t)sl * (128 * 1024);
    const u16* Bpanel = W2T + (size_t)n0 * 1024;
    for (int k0 = 0; k0 < 1024; k0 += 64) {
        stage_tile(Apanel + k0, 1024, As, tid);
        stage_tile(Bpanel + k0, 1024, Bs, tid);
        __syncthreads();
        mfma_block(As, Bs, acc, wr, wc, lane);
        __syncthreads();
    }

    // Fused diag contraction: C layout col = lane&15, row = (lane>>4)*4 + r
#pragma unroll
    for (int it = 0; it < 4; ++it) {
#pragma unroll
        for (int r = 0; r < 4; ++r) {
            int i = wr * 64 + it * 16 + lr * 4 + r;
            float p = 0.f;
#pragma unroll
            for (int kt = 0; kt < 4; ++kt) {
                int k2l = wc * 64 + kt * 16 + lc;
                float w3 = bfu(W3T[(size_t)i * 1024 + n0 + k2l]);
                p += acc[it][kt][r] * g2s[k2l] * w3;
            }
#pragma unroll
            for (int m = 1; m < 16; m <<= 1) p += __shfl_xor(p, m, 64);
            if (lc == 0) jtmp[wc][i] = p;
        }
    }
    __syncthreads();
    if (tid < 128)
        Jpart[((size_t)b * 8 + kb) * 128 + tid] = jtmp[0][tid] + jtmp[1][tid];
}

// sigma_drift and log-density drift.
__global__ __launch_bounds__(128) void k_final(const float* states, const float* Jpart,
                                               const float* Qws, float* out) {
    int b = blockIdx.x, i = threadIdx.x;
    float jd = 0.f;
#pragma unroll
    for (int kb = 0; kb < 8; ++kb) jd += Jpart[((size_t)b * 8 + kb) * 128 + i];
    float sig = states[(size_t)b * 256 + 128 + i];
    float q = Qws[(size_t)b * 128 + i];
    out[(size_t)b * 256 + 128 + i] = 2.f * jd * sig + q;
    float s1 = jd;
    float s2 = q / (sig + 1e-6f);
#pragma unroll
    for (int m = 32; m >= 1; m >>= 1) {
        s1 += __shfl_down(s1, m, 64);
        s2 += __shfl_down(s2, m, 64);
    }
    __shared__ float red[4];
    int wv = i >> 6, ln = i & 63;
    if (ln == 0) { red[wv * 2] = s1; red[wv * 2 + 1] = s2; }
    __syncthreads();
    if (i == 0) out[(size_t)NB * 256 + b] = -(red[0] + red[2]) + 0.5f * (red[1] + red[3]);
}

extern "C" void kernel_launch(void* const* d_in, const int* in_sizes, int n_in,
                              void* d_out, int out_size, void* d_ws, size_t ws_size,
                              hipStream_t stream) {
    (void)in_sizes; (void)n_in; (void)out_size;
    const float* states = (const float*)d_in[0];
    const float* tptr   = (const float*)d_in[1];
    const float* dW1 = (const float*)d_in[2];  const float* db1 = (const float*)d_in[3];
    const float* dW2 = (const float*)d_in[4];  const float* db2 = (const float*)d_in[5];
    const float* dW3 = (const float*)d_in[6];  const float* db3 = (const float*)d_in[7];
    const float* nW1 = (const float*)d_in[8];  const float* nb1 = (const float*)d_in[9];
    const float* nW2 = (const float*)d_in[10]; const float* nb2 = (const float*)d_in[11];
    const float* nW3 = (const float*)d_in[12]; const float* nb3 = (const float*)d_in[13];
    float* out = (float*)d_out;
    char* ws = (char*)d_ws;

    // workspace layout (bytes)
    u16* dW1bf = (u16*)(ws + 0);          //  128x1024 bf16      256 KiB
    u16* dW2T  = (u16*)(ws + 262144);     // 1024x1024 bf16 (T)    2 MiB
    u16* nW2T  = (u16*)(ws + 2359296);    //                       2 MiB
    u16* dW3T  = (u16*)(ws + 4456448);    //  128x1024 bf16 (T)  256 KiB
    u16* nW3T  = (u16*)(ws + 4718592);    //                     256 KiB
    u16* h1d   = (u16*)(ws + 4980736);    // 1024x1024 bf16        2 MiB
    u16* h1n   = (u16*)(ws + 7077888);
    u16* h2d   = (u16*)(ws + 9175040);
    u16* h2n   = (u16*)(ws + 11272192);
    float* Qws   = (float*)(ws + 13369344);  // 1024x128 f32      512 KiB
    float* Jpart = (float*)(ws + 13893632);  // 1024x8x128 f32      4 MiB
    u16* g1d   = (u16*)(ws + 18087936);   // 1024x1024 bf16        2 MiB
    u16* Asc   = (u16*)(ws + 20185088);   // CS x 128 x 1024 bf16 (chunked)
    const size_t ASC_OFF = 20185088;

    // chunk size: largest power-of-2 samples (>=64) whose Asc fits in ws
    int CS = 1024;
    while (CS > 64 && ASC_OFF + (size_t)CS * 262144 > ws_size) CS >>= 1;

    k_cast<<<512, 256, 0, stream>>>(dW1, dW1bf, 128 * 1024);
    dim3 tb(32, 8);
    k_transpose<<<dim3(32, 32), tb, 0, stream>>>(dW2, dW2T, 1024, 1024);
    k_transpose<<<dim3(32, 32), tb, 0, stream>>>(nW2, nW2T, 1024, 1024);
    k_transpose<<<dim3(4, 32), tb, 0, stream>>>(dW3, dW3T, 1024, 128);
    k_transpose<<<dim3(4, 32), tb, 0, stream>>>(nW3, nW3T, 1024, 128);
    k_layer1<<<dim3(128, 4, 2), 256, 0, stream>>>(states, tptr, dW1, db1, nW1, nb1,
                                                  h1d, h1n, g1d);
    k_gemm_tanh<<<dim3(8, 8, 2), 256, 0, stream>>>(h1d, h1n, dW2T, nW2T, db2, nb2, h2d, h2n);
    k_gemm_l3<<<dim3(1, 8, 2), 256, 0, stream>>>(h2d, h2n, dW3T, nW3T, db3, nb3, out, Qws);
    for (int c0 = 0; c0 < NB; c0 += CS) {
        k_scaleA<<<CS, 256, 0, stream>>>(dW1bf, g1d, Asc, c0);
        k_jacgemm<<<CS * 8, 256, 0, stream>>>(Asc, dW2T, dW3T, h2d, Jpart, c0, CS);
    }
    k_final<<<1024, 128, 0, stream>>>(states, Jpart, Qws, out);
}

// Round 3
// 444.059 us; speedup vs baseline: 1.9608x; 1.6944x over previous
//
#include <hip/hip_runtime.h>
#include <math.h>

typedef unsigned short u16;
typedef unsigned int u32;
typedef __bf16 bf16x8 __attribute__((ext_vector_type(8)));
typedef float f32x4 __attribute__((ext_vector_type(4)));

#define NB 1024   // batch
#define HID 1024

__device__ __forceinline__ float bfu(u16 u) { return __uint_as_float(((u32)u) << 16); }
__device__ __forceinline__ u16 f2bf(float f) {
    u32 u = __float_as_uint(f);
    return (u16)((u + 0x7fffu + ((u >> 16) & 1u)) >> 16);
}
__device__ __forceinline__ u32 pack2(float a, float b) {
    return (u32)f2bf(a) | ((u32)f2bf(b) << 16);
}
__device__ __forceinline__ void unpack8(uint4 v, float* f) {
    f[0] = bfu((u16)(v.x & 0xffffu)); f[1] = bfu((u16)(v.x >> 16));
    f[2] = bfu((u16)(v.y & 0xffffu)); f[3] = bfu((u16)(v.y >> 16));
    f[4] = bfu((u16)(v.z & 0xffffu)); f[5] = bfu((u16)(v.z >> 16));
    f[6] = bfu((u16)(v.w & 0xffffu)); f[7] = bfu((u16)(v.w >> 16));
}

#if __has_builtin(__builtin_amdgcn_global_load_lds)
#define HAVE_GLL 1
#else
#define HAVE_GLL 0
#endif

// Stage 16B per lane: global -> LDS. ldsbase must be wave-uniform; HW (or
// fallback) writes to ldsbase + lane*16.
__device__ __forceinline__ void stage16(const void* g, void* ldsbase, int lane) {
#if HAVE_GLL
    typedef const __attribute__((address_space(1))) unsigned char ga_t;
    typedef __attribute__((address_space(3))) unsigned char la_t;
    __builtin_amdgcn_global_load_lds((ga_t*)(unsigned long long)g,
                                     (la_t*)(u32)(unsigned long long)ldsbase,
                                     16, 0, 0);
#else
    *reinterpret_cast<uint4*>((char*)ldsbase + lane * 16) =
        *reinterpret_cast<const uint4*>(g);
#endif
}

// ---------------- 128x128-tile helpers (4 waves, 2x2) -------------------

// Stage a 128 x 64 bf16 tile (rows from a row-major source with leading dim
// ld, 64 contiguous elements each) into dst[128*64] (row stride 64). Linear.
__device__ __forceinline__ void stage_tile(const u16* src, int ld, u16* dst, int tid) {
    int w = tid >> 6, lane = tid & 63;
#pragma unroll
    for (int q = 0; q < 4; ++q) {
        int rbase = q * 32 + w * 8;
        int row = rbase + (lane >> 3);
        stage16(src + (size_t)row * ld + (lane & 7) * 8, dst + rbase * 64, lane);
    }
}

// 4 waves (2x2), each wave computes a 64x64 sub-tile as 4x4 fragments of
// 16x16x32 bf16 MFMA. As/Bs are [128][64] bf16 (A rows = M, B rows = N).
__device__ __forceinline__ void mfma_block(const u16* As, const u16* Bs,
                                           f32x4 acc[4][4], int wr, int wc, int lane) {
    int lr = lane >> 4, lc = lane & 15;
#pragma unroll
    for (int kc = 0; kc < 64; kc += 32) {
        bf16x8 av[4], bv[4];
#pragma unroll
        for (int it = 0; it < 4; ++it)
            av[it] = *(const bf16x8*)&As[(wr * 64 + it * 16 + lc) * 64 + kc + lr * 8];
#pragma unroll
        for (int nt = 0; nt < 4; ++nt)
            bv[nt] = *(const bf16x8*)&Bs[(wc * 64 + nt * 16 + lc) * 64 + kc + lr * 8];
#pragma unroll
        for (int it = 0; it < 4; ++it)
#pragma unroll
            for (int nt = 0; nt < 4; ++nt)
                acc[it][nt] = __builtin_amdgcn_mfma_f32_16x16x32_bf16(
                    av[it], bv[nt], acc[it][nt], 0, 0, 0);
    }
}

// ---------------------------- prep kernels ------------------------------

__global__ __launch_bounds__(256) void k_cast(const float* in, u16* out, int n) {
    int i = blockIdx.x * 256 + threadIdx.x;
    if (i < n) out[i] = f2bf(in[i]);
}

// out[c*R + r] = bf16(in[r*C + c]); R,C multiples of 32. z selects pair.
__global__ __launch_bounds__(256) void k_transposeB(const float* inA, const float* inB,
                                                    u16* outA, u16* outB, int R, int C) {
    const float* in = blockIdx.z ? inB : inA;
    u16* out = blockIdx.z ? outB : outA;
    __shared__ u16 tile[32][33];
    int c0 = blockIdx.x * 32, r0 = blockIdx.y * 32;
    int tx = threadIdx.x, ty = threadIdx.y;  // (32, 8)
#pragma unroll
    for (int dy = 0; dy < 32; dy += 8)
        tile[ty + dy][tx] = f2bf(in[(size_t)(r0 + ty + dy) * C + c0 + tx]);
    __syncthreads();
#pragma unroll
    for (int dy = 0; dy < 32; dy += 8)
        out[(size_t)(c0 + ty + dy) * R + r0 + tx] = tile[tx][ty + dy];
}

// Layer 1, fp32: h1 = tanh([mu,t] @ W1 + b1) for drift and noise nets.
// grid (128 sample-groups, 4 col-quarters, 2 nets); 8 samples per block.
// Also emits g1 = 1 - h1^2 (bf16) for the drift net.
__global__ __launch_bounds__(256) void k_layer1(const float* states, const float* tptr,
                                                const float* dW1, const float* db1,
                                                const float* nW1, const float* nb1,
                                                u16* h1d, u16* h1n, u16* g1d) {
    __shared__ float xt[129][8];
    int blk = blockIdx.x, q = blockIdx.y, net = blockIdx.z, tid = threadIdx.x;
    float t = *tptr;
    for (int idx = tid; idx < 8 * 128; idx += 256) {
        int d = idx >> 3, s = idx & 7;
        xt[d][s] = states[(size_t)(blk * 8 + s) * 256 + d];
    }
    if (tid < 8) xt[128][tid] = t;
    __syncthreads();
    const float* W = net ? nW1 : dW1;
    const float* bi = net ? nb1 : db1;
    u16* H = net ? h1n : h1d;
    int o = q * 256 + tid;
    float acc[8] = {0.f, 0.f, 0.f, 0.f, 0.f, 0.f, 0.f, 0.f};
    for (int d = 0; d < 129; ++d) {
        float w = W[(size_t)d * 1024 + o];
        float4 xa = *(const float4*)&xt[d][0];
        float4 xb = *(const float4*)&xt[d][4];
        acc[0] += xa.x * w; acc[1] += xa.y * w; acc[2] += xa.z * w; acc[3] += xa.w * w;
        acc[4] += xb.x * w; acc[5] += xb.y * w; acc[6] += xb.z * w; acc[7] += xb.w * w;
    }
    float b = bi[o];
#pragma unroll
    for (int s = 0; s < 8; ++s) {
        float h = tanhf(acc[s] + b);
        H[(size_t)(blk * 8 + s) * 1024 + o] = f2bf(h);
        if (!net) g1d[(size_t)(blk * 8 + s) * 1024 + o] = f2bf(1.f - h * h);
    }
}

// Layer 2 partial: P[net][ks] = h1 @ W2[kslice]  (f32 partials, K-split 2).
// grid (16 = nt + 8*ks, 8 m-tiles, 2 nets), 256 threads.
__global__ __launch_bounds__(256) void k_l2part(const u16* Ad, const u16* An,
                                                const u16* Wd, const u16* Wn,
                                                float* P) {
    int x = blockIdx.x;
    int nt = x & 7, ks = x >> 3;
    int mt = blockIdx.y, net = blockIdx.z;
    const u16* A = net ? An : Ad;
    const u16* W = net ? Wn : Wd;
    int n0 = nt * 128, row0 = mt * 128;
    int kbeg = ks * 512;
    __shared__ __align__(16) u16 As[128 * 64], Bs[128 * 64];
    int tid = threadIdx.x, w = tid >> 6, lane = tid & 63;
    int wr = w >> 1, wc = w & 1, lr = lane >> 4, lc = lane & 15;
    f32x4 acc[4][4];
#pragma unroll
    for (int a = 0; a < 4; ++a)
#pragma unroll
        for (int b2 = 0; b2 < 4; ++b2) { f32x4 zz = {0.f, 0.f, 0.f, 0.f}; acc[a][b2] = zz; }
    for (int k0 = kbeg; k0 < kbeg + 512; k0 += 64) {
        stage_tile(A + (size_t)row0 * 1024 + k0, 1024, As, tid);
        stage_tile(W + (size_t)n0 * 1024 + k0, 1024, Bs, tid);
        __syncthreads();
        mfma_block(As, Bs, acc, wr, wc, lane);
        __syncthreads();
    }
    float* dst = P + (size_t)(net * 2 + ks) * 1024 * 1024;
#pragma unroll
    for (int it = 0; it < 4; ++it)
#pragma unroll
        for (int nt2 = 0; nt2 < 4; ++nt2) {
            int col = n0 + wc * 64 + nt2 * 16 + lc;
#pragma unroll
            for (int r = 0; r < 4; ++r) {
                int row = row0 + wr * 64 + it * 16 + lr * 4 + r;
                dst[(size_t)row * 1024 + col] = acc[it][nt2][r];
            }
        }
}

// h2 = tanh(P0 + P1 + b2) -> bf16. grid (4096, 2 nets), 256 thr.
__global__ __launch_bounds__(256) void k_h2fin(const float* P, const float* db2,
                                               const float* nb2, u16* h2d, u16* h2n) {
    int net = blockIdx.y;
    const float* b = net ? nb2 : db2;
    u16* H = net ? h2n : h2d;
    size_t idx = (size_t)blockIdx.x * 256 + threadIdx.x;  // < 1M
    int col = (int)(idx & 1023);
    const float* P0 = P + (size_t)(net * 2) * 1024 * 1024;
    const float* P1 = P + (size_t)(net * 2 + 1) * 1024 * 1024;
    H[idx] = f2bf(tanhf(P0[idx] + P1[idx] + b[col]));
}

// Layer 3 partial: L3[net][ks] = h2 @ W3[kslice] (f32 partials, K-split 4).
// grid (4 ks, 8 m-tiles, 2 nets), 256 threads. N = 128 (single n-tile).
__global__ __launch_bounds__(256) void k_l3part(const u16* Ad, const u16* An,
                                                const u16* Wd, const u16* Wn,
                                                float* P) {
    int ks = blockIdx.x, mt = blockIdx.y, net = blockIdx.z;
    const u16* A = net ? An : Ad;
    const u16* W = net ? Wn : Wd;
    int row0 = mt * 128, kbeg = ks * 256;
    __shared__ __align__(16) u16 As[128 * 64], Bs[128 * 64];
    int tid = threadIdx.x, w = tid >> 6, lane = tid & 63;
    int wr = w >> 1, wc = w & 1, lr = lane >> 4, lc = lane & 15;
    f32x4 acc[4][4];
#pragma unroll
    for (int a = 0; a < 4; ++a)
#pragma unroll
        for (int b2 = 0; b2 < 4; ++b2) { f32x4 zz = {0.f, 0.f, 0.f, 0.f}; acc[a][b2] = zz; }
    for (int k0 = kbeg; k0 < kbeg + 256; k0 += 64) {
        stage_tile(A + (size_t)row0 * 1024 + k0, 1024, As, tid);
        stage_tile(W + (size_t)k0, 1024, Bs, tid);
        __syncthreads();
        mfma_block(As, Bs, acc, wr, wc, lane);
        __syncthreads();
    }
    float* dst = P + (size_t)(net * 4 + ks) * 1024 * 128;
#pragma unroll
    for (int it = 0; it < 4; ++it)
#pragma unroll
        for (int nt2 = 0; nt2 < 4; ++nt2) {
            int col = wc * 64 + nt2 * 16 + lc;
#pragma unroll
            for (int r = 0; r < 4; ++r) {
                int row = row0 + wr * 64 + it * 16 + lr * 4 + r;
                dst[(size_t)row * 128 + col] = acc[it][nt2][r];
            }
        }
}

// Materialize Asc[s_local][i][j] = dW1bf[i][j] * g1[b][j]  (bf16).
__global__ __launch_bounds__(256) void k_scaleA(const u16* dW1bf, const u16* g1d,
                                                u16* Asc, int c0) {
    int sl = blockIdx.x;
    size_t b = (size_t)(c0 + sl);
    const u16* g1 = g1d + b * 1024;
    u16* dst = Asc + (size_t)sl * (128 * 1024);
    int tid = threadIdx.x;
    for (int idx = tid; idx < 128 * 128; idx += 256) {
        int row = idx >> 7, jc = idx & 127;
        int j0 = jc * 8;
        uint4 wv = *(const uint4*)&dW1bf[(size_t)row * 1024 + j0];
        uint4 gv = *(const uint4*)&g1[j0];
        float wf[8], gf[8];
        unpack8(wv, wf);
        unpack8(gv, gf);
        uint4 o;
        o.x = pack2(wf[0] * gf[0], wf[1] * gf[1]);
        o.y = pack2(wf[2] * gf[2], wf[3] * gf[3]);
        o.z = pack2(wf[4] * gf[4], wf[5] * gf[5]);
        o.w = pack2(wf[6] * gf[6], wf[7] * gf[7]);
        *(uint4*)&dst[(size_t)row * 1024 + j0] = o;
    }
}

// ------------------- 256x256 double-buffered jac GEMM -------------------
// 512 threads = 8 waves (2 M x 4 N). Per-wave output 128x64 (8x4 fragments).
// LDS: 2 bufs x (A 256x64 + B 256x64) bf16 = 128 KiB.
// T2 swizzle: LDS linear (global_load_lds), global SOURCE 16B-chunk permuted
// by c ^= (row&7); ds_read applies the same XOR -> conflict-free (2-way).

// Stage one 256x64 tile. dst = LDS tile base (16384 u16). panel ld = 1024.
__device__ __forceinline__ void stage256(const u16* panel, int k0, u16* dst, int tid) {
    int lane = tid & 63, w = tid >> 6;
#pragma unroll
    for (int q = 0; q < 4; ++q) {
        int Dhalf = q * 4096 + w * 512 + lane * 8;   // dest offset in u16
        int row = Dhalf >> 6;                        // 64 u16 per row
        int chunk = (Dhalf >> 3) & 7;
        int src_chunk = chunk ^ (row & 7);
        stage16(panel + (size_t)row * 1024 + k0 + src_chunk * 8,
                dst + q * 4096 + w * 512, lane);
    }
}

__device__ __forceinline__ void compute256(const u16* As, const u16* Bs,
                                           f32x4 acc[8][4], int wr, int wc, int lane) {
    int lr = lane >> 4, lc = lane & 15;
#pragma unroll
    for (int kh = 0; kh < 2; ++kh) {
        bf16x8 av[8], bv[4];
#pragma unroll
        for (int m = 0; m < 8; ++m) {
            int row = wr * 128 + m * 16 + lc;
            int chunk = (kh * 4 + lr) ^ (row & 7);
            av[m] = *(const bf16x8*)&As[row * 64 + chunk * 8];
        }
#pragma unroll
        for (int n = 0; n < 4; ++n) {
            int row = wc * 64 + n * 16 + lc;
            int chunk = (kh * 4 + lr) ^ (row & 7);
            bv[n] = *(const bf16x8*)&Bs[row * 64 + chunk * 8];
        }
#pragma unroll
        for (int m = 0; m < 8; ++m)
#pragma unroll
            for (int n = 0; n < 4; ++n)
                acc[m][n] = __builtin_amdgcn_mfma_f32_16x16x32_bf16(
                    av[m], bv[n], acc[m][n], 0, 0, 0);
    }
}

__global__ __launch_bounds__(512, 2) void k_jac256(const u16* Asc, const u16* W2T,
                                                   const u16* W3T, const u16* h2d,
                                                   float* Jpart, int c0, int CS) {
    __shared__ __align__(16) u16 smem[2][2][16384];
    int tid = threadIdx.x, lane = tid & 63, w = tid >> 6;
    int wr = w >> 2, wc = w & 3, lr = lane >> 4, lc = lane & 15;
    int nwg = 2 * CS;
    int hID = blockIdx.x;
    int lin = (hID & 7) * (nwg >> 3) + (hID >> 3);   // XCD-contiguous remap
    int mt = lin >> 2, nt = lin & 3;
    int n0 = nt * 256;
    const u16* Apanel = Asc + (size_t)mt * 256 * 1024;
    const u16* Bpanel = W2T + (size_t)n0 * 1024;

    f32x4 acc[8][4];
#pragma unroll
    for (int m = 0; m < 8; ++m)
#pragma unroll
        for (int n = 0; n < 4; ++n) { f32x4 zz = {0.f, 0.f, 0.f, 0.f}; acc[m][n] = zz; }

    stage256(Apanel, 0, smem[0][0], tid);
    stage256(Bpanel, 0, smem[0][1], tid);
    __syncthreads();

    for (int t = 0; t < 16; ++t) {
        int p = t & 1;
        if (t < 15) {
            stage256(Apanel, (t + 1) * 64, smem[p ^ 1][0], tid);
            stage256(Bpanel, (t + 1) * 64, smem[p ^ 1][1], tid);
        }
        __builtin_amdgcn_s_setprio(1);
        compute256(smem[p][0], smem[p][1], acc, wr, wc, lane);
        __builtin_amdgcn_s_setprio(0);
        __syncthreads();
    }

    // Fused diagonal contraction.
    // C mapping: row(i) = m*16 + lr*4 + r (sample = 2*mt + wr), col(k2) =
    // n0 + wc*64 + n*16 + lc.
    int b = c0 + 2 * mt + wr;
    float g2v[4];
#pragma unroll
    for (int n = 0; n < 4; ++n) {
        int k2 = n0 + wc * 64 + n * 16 + lc;
        float h2 = bfu(h2d[(size_t)b * 1024 + k2]);
        g2v[n] = 1.f - h2 * h2;
    }
    float* jtmp = (float*)&smem[0][0][0];   // [4][256]
#pragma unroll
    for (int m = 0; m < 8; ++m) {
#pragma unroll
        for (int r = 0; r < 4; ++r) {
            int i = m * 16 + lr * 4 + r;
            float p = 0.f;
#pragma unroll
            for (int n = 0; n < 4; ++n) {
                int k2 = n0 + wc * 64 + n * 16 + lc;
                float w3 = bfu(W3T[(size_t)i * 1024 + k2]);
                p += acc[m][n][r] * g2v[n] * w3;
            }
#pragma unroll
            for (int msk = 1; msk < 16; msk <<= 1) p += __shfl_xor(p, msk, 64);
            if (lc == 0) jtmp[wc * 256 + wr * 128 + i] = p;
        }
    }
    __syncthreads();
    if (tid < 256) {
        float s = jtmp[tid] + jtmp[256 + tid] + jtmp[512 + tid] + jtmp[768 + tid];
        int bb = c0 + 2 * mt + (tid >> 7);
        Jpart[((size_t)bb * 4 + nt) * 128 + (tid & 127)] = s;
    }
}

// ------------------------------ finalize --------------------------------
// mu_drift, sigma_drift, log-density drift.
__global__ __launch_bounds__(128) void k_final(const float* states, const float* Jpart,
                                               const float* L3part, const float* db3,
                                               const float* nb3, float* out) {
    int b = blockIdx.x, i = threadIdx.x;
    float jd = 0.f;
#pragma unroll
    for (int kb = 0; kb < 4; ++kb) jd += Jpart[((size_t)b * 4 + kb) * 128 + i];
    float mu = db3[i], qr = nb3[i];
#pragma unroll
    for (int ks = 0; ks < 4; ++ks) {
        mu += L3part[((size_t)(0 * 4 + ks) * 1024 + b) * 128 + i];
        qr += L3part[((size_t)(1 * 4 + ks) * 1024 + b) * 128 + i];
    }
    out[(size_t)b * 256 + i] = mu;
    float q = (qr > 20.f) ? qr : log1pf(expf(qr));
    float sig = states[(size_t)b * 256 + 128 + i];
    out[(size_t)b * 256 + 128 + i] = 2.f * jd * sig + q;
    float s1 = jd;
    float s2 = q / (sig + 1e-6f);
#pragma unroll
    for (int m = 32; m >= 1; m >>= 1) {
        s1 += __shfl_down(s1, m, 64);
        s2 += __shfl_down(s2, m, 64);
    }
    __shared__ float red[4];
    int wv = i >> 6, ln = i & 63;
    if (ln == 0) { red[wv * 2] = s1; red[wv * 2 + 1] = s2; }
    __syncthreads();
    if (i == 0) out[(size_t)NB * 256 + b] = -(red[0] + red[2]) + 0.5f * (red[1] + red[3]);
}

extern "C" void kernel_launch(void* const* d_in, const int* in_sizes, int n_in,
                              void* d_out, int out_size, void* d_ws, size_t ws_size,
                              hipStream_t stream) {
    (void)in_sizes; (void)n_in; (void)out_size;
    const float* states = (const float*)d_in[0];
    const float* tptr   = (const float*)d_in[1];
    const float* dW1 = (const float*)d_in[2];  const float* db1 = (const float*)d_in[3];
    const float* dW2 = (const float*)d_in[4];  const float* db2 = (const float*)d_in[5];
    const float* dW3 = (const float*)d_in[6];  const float* db3 = (const float*)d_in[7];
    const float* nW1 = (const float*)d_in[8];  const float* nb1 = (const float*)d_in[9];
    const float* nW2 = (const float*)d_in[10]; const float* nb2 = (const float*)d_in[11];
    const float* nW3 = (const float*)d_in[12]; const float* nb3 = (const float*)d_in[13];
    float* out = (float*)d_out;
    char* ws = (char*)d_ws;

    // workspace layout (bytes)
    u16* dW1bf = (u16*)(ws + 0);           //  128x1024 bf16     256 KiB
    u16* dW2T  = (u16*)(ws + 262144);      // 1024x1024 bf16 (T)   2 MiB
    u16* nW2T  = (u16*)(ws + 2359296);     //                      2 MiB
    u16* dW3T  = (u16*)(ws + 4456448);     //  128x1024 bf16 (T) 256 KiB
    u16* nW3T  = (u16*)(ws + 4718592);     //                    256 KiB
    u16* h1d   = (u16*)(ws + 4980736);     // 1024x1024 bf16       2 MiB
    u16* h1n   = (u16*)(ws + 7077888);
    u16* h2d   = (u16*)(ws + 9175040);
    u16* h2n   = (u16*)(ws + 11272192);
    u16* g1d   = (u16*)(ws + 13369344);    // 1024x1024 bf16       2 MiB
    float* Jpart  = (float*)(ws + 15466496);  // 1024x4x128 f32    2 MiB
    float* L3part = (float*)(ws + 17563648);  // 2x4x1024x128 f32  4 MiB
    float* H2part = (float*)(ws + 21757952);  // 2x2x1024x1024 f32 16 MiB
    u16* Asc   = (u16*)(ws + 38535168);    // CS x 128 x 1024 bf16 (chunked)
    const size_t ASC_OFF = 38535168;

    int CS = 1024;
    while (CS > 64 && ASC_OFF + (size_t)CS * 262144 > ws_size) CS >>= 1;

    k_cast<<<512, 256, 0, stream>>>(dW1, dW1bf, 128 * 1024);
    dim3 tb(32, 8);
    k_transposeB<<<dim3(32, 32, 2), tb, 0, stream>>>(dW2, nW2, dW2T, nW2T, 1024, 1024);
    k_transposeB<<<dim3(4, 32, 2), tb, 0, stream>>>(dW3, nW3, dW3T, nW3T, 1024, 128);
    k_layer1<<<dim3(128, 4, 2), 256, 0, stream>>>(states, tptr, dW1, db1, nW1, nb1,
                                                  h1d, h1n, g1d);
    k_l2part<<<dim3(16, 8, 2), 256, 0, stream>>>(h1d, h1n, dW2T, nW2T, H2part);
    k_h2fin<<<dim3(4096, 2), 256, 0, stream>>>(H2part, db2, nb2, h2d, h2n);
    k_l3part<<<dim3(4, 8, 2), 256, 0, stream>>>(h2d, h2n, dW3T, nW3T, L3part);
    for (int c0 = 0; c0 < NB; c0 += CS) {
        k_scaleA<<<CS, 256, 0, stream>>>(dW1bf, g1d, Asc, c0);
        k_jac256<<<2 * CS, 512, 0, stream>>>(Asc, dW2T, dW3T, h2d, Jpart, c0, CS);
    }
    k_final<<<1024, 128, 0, stream>>>(states, Jpart, L3part, db3, nb3, out);
}